// Round 3
// baseline (681.145 us; speedup 1.0000x reference)
//
#include <hip/hip_runtime.h>
#include <math.h>

#define NB 2
#define NCH 192
#define NH 48
#define NW 48
#define NL 2304
#define NK 4
#define NN 16
#define NR 12
#define ND 44
#define NDP 48
#define NCHUNK 96
#define CLEN 24     // NL / NCHUNK
#define NBLK (NB * NK * NCHUNK)   // 768 scan blocks

// workspace float sizes
#define SZ_XT    (NB * NCH * NL)                 // 884736
#define SZ_UT0   (NB * NL * NCH)                 // 884736
#define SZ_BC    (NB * NK * NL * 32)             // 589824
#define SZ_DELTA (NB * NK * NL * NCH)            // 3538944
#define SZ_YBUF  (NB * NK * NL * NCH)            // 3538944
#define SZ_PUB   (NBLK * NCH * NN)               // 2359296

// --------------------------------------------- prep: xT, ut0, flag clear
__global__ __launch_bounds__(256) void k_prep(const float* __restrict__ x,
                                              float* __restrict__ xT,
                                              float* __restrict__ ut0,
                                              unsigned* __restrict__ flags) {
    __shared__ float tile[64 * 193];
    int bid = blockIdx.x;
    if (bid < NB * NCH) {
        // xT[b][c][w*48+h] = x[b][c][h*48+w]
        const float* src = x + (size_t)bid * NL;
        float* dst = xT + (size_t)bid * NL;
        for (int i = threadIdx.x; i < NL; i += 256) {
            int h = i / NW, w = i % NW;
            tile[w * 49 + h] = src[i];
        }
        __syncthreads();
        for (int i = threadIdx.x; i < NL; i += 256) {
            dst[i] = tile[i + i / NH];
        }
    } else {
        int t = bid - NB * NCH;                // 0..71
        if (t == 0) {
            for (int i = threadIdx.x; i < NBLK; i += 256) flags[i] = 0u;
        }
        int b = t / 36, lt = t % 36;
        int l0 = lt * 64;
        const float* bx = x + (size_t)b * NCH * NL;
        for (int i = threadIdx.x; i < NCH * 64; i += 256) {
            int c = i >> 6, j = i & 63;        // coalesced read along l
            tile[j * 193 + c] = bx[(size_t)c * NL + l0 + j];
        }
        __syncthreads();
        float* bo = ut0 + (size_t)b * NL * NCH;
        for (int i = threadIdx.x; i < NCH * 64; i += 256) {
            int j = i / NCH, c = i % NCH;      // coalesced write along c
            bo[(size_t)(l0 + j) * NCH + c] = tile[j * 193 + c];
        }
    }
}

// --------------------- proj: BC[bk][l][32] (B then C) + delta[bk][l][c] fused
__global__ __launch_bounds__(192) void k_proj(const float* __restrict__ x,
                                              const float* __restrict__ xT,
                                              const float* __restrict__ xpw,
                                              const float* __restrict__ dtw,
                                              const float* __restrict__ dt_bias,
                                              float* __restrict__ BC,
                                              float* __restrict__ delta) {
    int bid = blockIdx.x;                      // 8 * 36
    int bk = bid / 36;
    int lt0 = (bid % 36) * 64;
    int b = bk >> 2, k = bk & 3;
    int tid = threadIdx.x;
    int lt = tid & 15;
    int dt = tid >> 4;                         // 0..11
    __shared__ float WT[NCH * NDP];            // 36.9 KB
    __shared__ float XS[48 * 64];              // 12.3 KB
    __shared__ float DT[64 * NR];              // 3.0 KB
    for (int i = tid; i < NCH * NDP; i += 192) {
        int c = i / NDP, d = i % NDP;
        WT[i] = (d < ND) ? xpw[((size_t)k * ND + d) * NCH + c] : 0.0f;
    }
    const float* bx = ((k & 1) ? xT : x) + (size_t)b * NCH * NL;
    bool rev = (k >= 2);
    float acc[16];
#pragma unroll
    for (int i = 0; i < 16; ++i) acc[i] = 0.0f;
    for (int ch = 0; ch < 4; ++ch) {
        int c0 = ch * 48;
        __syncthreads();
        for (int i = tid; i < 48 * 64; i += 192) {
            int cc = i >> 6, j = i & 63;
            int gl = lt0 + j;
            if (rev) gl = NL - 1 - gl;
            XS[i] = bx[(size_t)(c0 + cc) * NL + gl];
        }
        __syncthreads();
#pragma unroll 4
        for (int cc = 0; cc < 48; ++cc) {
            float4 wv = *(const float4*)&WT[(c0 + cc) * NDP + dt * 4];
            float4 xv = *(const float4*)&XS[cc * 64 + lt * 4];
            float xa[4] = {xv.x, xv.y, xv.z, xv.w};
            float wa[4] = {wv.x, wv.y, wv.z, wv.w};
#pragma unroll
            for (int li = 0; li < 4; ++li)
#pragma unroll
                for (int di = 0; di < 4; ++di)
                    acc[li * 4 + di] = fmaf(xa[li], wa[di], acc[li * 4 + di]);
        }
    }
    // d 0..11 -> DT (LDS only); d 12..43 -> BC global (compacted by -12)
    if (dt < 3) {
#pragma unroll
        for (int li = 0; li < 4; ++li) {
            float4 o = make_float4(acc[li * 4 + 0], acc[li * 4 + 1],
                                   acc[li * 4 + 2], acc[li * 4 + 3]);
            *(float4*)&DT[(lt * 4 + li) * NR + dt * 4] = o;
        }
    } else if (dt < 11) {
#pragma unroll
        for (int li = 0; li < 4; ++li) {
            int l = lt0 + lt * 4 + li;
            float4 o = make_float4(acc[li * 4 + 0], acc[li * 4 + 1],
                                   acc[li * 4 + 2], acc[li * 4 + 3]);
            *(float4*)&BC[((size_t)bk * NL + l) * 32 + (dt * 4 - 12)] = o;
        }
    }
    __syncthreads();
    // delta for this l-tile: c = tid
    int c = tid;
    const float4* wp = (const float4*)(dtw + ((size_t)k * NCH + c) * NR);
    float4 w0 = wp[0], w1 = wp[1], w2 = wp[2];
    float bias = dt_bias[k * NCH + c];
    for (int l = 0; l < 64; ++l) {
        float4 a0 = *(const float4*)&DT[l * NR + 0];
        float4 a1 = *(const float4*)&DT[l * NR + 4];
        float4 a2 = *(const float4*)&DT[l * NR + 8];
        float acc2 = bias;
        acc2 = fmaf(w0.x, a0.x, acc2); acc2 = fmaf(w0.y, a0.y, acc2);
        acc2 = fmaf(w0.z, a0.z, acc2); acc2 = fmaf(w0.w, a0.w, acc2);
        acc2 = fmaf(w1.x, a1.x, acc2); acc2 = fmaf(w1.y, a1.y, acc2);
        acc2 = fmaf(w1.z, a1.z, acc2); acc2 = fmaf(w1.w, a1.w, acc2);
        acc2 = fmaf(w2.x, a2.x, acc2); acc2 = fmaf(w2.y, a2.y, acc2);
        acc2 = fmaf(w2.z, a2.z, acc2); acc2 = fmaf(w2.w, a2.w, acc2);
        float sp = fmaxf(acc2, 0.0f) + log1pf(expf(-fabsf(acc2)));
        delta[((size_t)bk * NL + lt0 + l) * NCH + c] = sp;
    }
}

__device__ __forceinline__ int u_row(int k, int l) {
    int pos = (k >= 2) ? (NL - 1 - l) : l;
    if (k & 1) pos = (pos % 48) * 48 + (pos / 48);
    return pos;
}

// ------------- fused scan: local scan + decoupled lookback + emit y
__global__ __launch_bounds__(192, 3) void k_scan(const float* __restrict__ ut0,
                                                 const float* __restrict__ BC,
                                                 const float* __restrict__ delta,
                                                 const float* __restrict__ A_logs,
                                                 const float* __restrict__ Ds,
                                                 float* __restrict__ PubP,
                                                 float* __restrict__ PubH,
                                                 float* __restrict__ PubI,
                                                 unsigned* __restrict__ flags,
                                                 float* __restrict__ ybuf) {
    int bid = blockIdx.x;
    int bk = bid / NCHUNK;
    int ch = bid % NCHUNK;
    int b = bk >> 2, k = bk & 3;
    int c = threadIdx.x;
    __shared__ float DL[CLEN * NCH];           // per-thread stage (no sharing)
    __shared__ float UVS[CLEN * NCH];
    float A2[NN];
    {
        const float4* ap = (const float4*)(A_logs + ((size_t)(k * NCH + c)) * NN);
        float4 a0 = ap[0], a1 = ap[1], a2 = ap[2], a3 = ap[3];
        float t[16] = {a0.x, a0.y, a0.z, a0.w, a1.x, a1.y, a1.z, a1.w,
                       a2.x, a2.y, a2.z, a2.w, a3.x, a3.y, a3.z, a3.w};
#pragma unroll
        for (int n = 0; n < NN; ++n) A2[n] = -expf(t[n]) * 1.44269504f;
    }
    float h[NN];
#pragma unroll
    for (int n = 0; n < NN; ++n) h[n] = 0.0f;
    float S = 0.0f;
    const float* dp = delta + (size_t)bk * NL * NCH + c;
    const float* up = ut0 + (size_t)b * NL * NCH + c;
    int l0 = ch * CLEN;
    for (int i = 0; i < CLEN; ++i) {
        int l = l0 + i;
        float dlt = dp[(size_t)l * NCH];
        float uv = up[(size_t)u_row(k, l) * NCH];
        DL[i * NCH + c] = dlt;
        UVS[i * NCH + c] = uv;
        float du = dlt * uv;
        S += dlt;
        const float4* br = (const float4*)(BC + ((size_t)bk * NL + l) * 32);
        float4 b0 = br[0], b1 = br[1], b2 = br[2], b3 = br[3];
        float Bv[16] = {b0.x, b0.y, b0.z, b0.w, b1.x, b1.y, b1.z, b1.w,
                        b2.x, b2.y, b2.z, b2.w, b3.x, b3.y, b3.z, b3.w};
#pragma unroll
        for (int n = 0; n < NN; ++n) {
            float dA = exp2f(dlt * A2[n]);
            h[n] = fmaf(dA, h[n], du * Bv[n]);
        }
    }
    float P[NN];
#pragma unroll
    for (int n = 0; n < NN; ++n) P[n] = exp2f(S * A2[n]);
    size_t pb = ((size_t)bid * NCH + c) * NN;
    if (ch > 0) {                              // publish partial
#pragma unroll
        for (int q = 0; q < 4; ++q) {
            *(float4*)&PubH[pb + q * 4] = make_float4(h[q*4], h[q*4+1], h[q*4+2], h[q*4+3]);
            *(float4*)&PubP[pb + q * 4] = make_float4(P[q*4], P[q*4+1], P[q*4+2], P[q*4+3]);
        }
        __threadfence();
        __syncthreads();
        if (threadIdx.x == 0)
            __hip_atomic_store(&flags[bid], 1u, __ATOMIC_RELEASE, __HIP_MEMORY_SCOPE_AGENT);
    }
    // lookback
    float Hin[NN];
    if (ch == 0) {
#pragma unroll
        for (int n = 0; n < NN; ++n) Hin[n] = 0.0f;
    } else {
        float accP[NN], accH[NN];
#pragma unroll
        for (int n = 0; n < NN; ++n) { accP[n] = 1.0f; accH[n] = 0.0f; }
        int j = bid - 1;
        while (true) {
            unsigned f;
            do {
                f = __hip_atomic_load(&flags[j], __ATOMIC_ACQUIRE, __HIP_MEMORY_SCOPE_AGENT);
            } while (f == 0u);
            size_t qb = ((size_t)j * NCH + c) * NN;
            if (f == 2u) {
#pragma unroll
                for (int q = 0; q < 4; ++q) {
                    float4 I = *(const float4*)&PubI[qb + q * 4];
                    float iv[4] = {I.x, I.y, I.z, I.w};
#pragma unroll
                    for (int d = 0; d < 4; ++d)
                        Hin[q * 4 + d] = fmaf(accP[q * 4 + d], iv[d], accH[q * 4 + d]);
                }
                break;
            } else {
#pragma unroll
                for (int q = 0; q < 4; ++q) {
                    float4 E = *(const float4*)&PubH[qb + q * 4];
                    float4 Pp = *(const float4*)&PubP[qb + q * 4];
                    float ev[4] = {E.x, E.y, E.z, E.w};
                    float pv[4] = {Pp.x, Pp.y, Pp.z, Pp.w};
#pragma unroll
                    for (int d = 0; d < 4; ++d) {
                        accH[q * 4 + d] = fmaf(accP[q * 4 + d], ev[d], accH[q * 4 + d]);
                        accP[q * 4 + d] *= pv[d];
                    }
                }
                --j;
            }
        }
    }
    // publish inclusive
#pragma unroll
    for (int q = 0; q < 4; ++q) {
        float4 I;
        I.x = fmaf(P[q*4+0], Hin[q*4+0], h[q*4+0]);
        I.y = fmaf(P[q*4+1], Hin[q*4+1], h[q*4+1]);
        I.z = fmaf(P[q*4+2], Hin[q*4+2], h[q*4+2]);
        I.w = fmaf(P[q*4+3], Hin[q*4+3], h[q*4+3]);
        *(float4*)&PubI[pb + q * 4] = I;
    }
    __threadfence();
    __syncthreads();
    if (threadIdx.x == 0)
        __hip_atomic_store(&flags[bid], 2u, __ATOMIC_RELEASE, __HIP_MEMORY_SCOPE_AGENT);
    // phase C: rescan from true incoming state, emit y
#pragma unroll
    for (int n = 0; n < NN; ++n) h[n] = Hin[n];
    float dval = Ds[k * NCH + c];
    float* yp = ybuf + (size_t)bk * NL * NCH + c;
    for (int i = 0; i < CLEN; ++i) {
        int l = l0 + i;
        float dlt = DL[i * NCH + c];
        float uv = UVS[i * NCH + c];
        float du = dlt * uv;
        const float* row = BC + ((size_t)bk * NL + l) * 32;
        const float4* br = (const float4*)row;
        float4 b0 = br[0], b1 = br[1], b2 = br[2], b3 = br[3];
        float Bv[16] = {b0.x, b0.y, b0.z, b0.w, b1.x, b1.y, b1.z, b1.w,
                        b2.x, b2.y, b2.z, b2.w, b3.x, b3.y, b3.z, b3.w};
        const float4* cr = (const float4*)(row + NN);
        float4 c0 = cr[0], c1 = cr[1], c2 = cr[2], c3 = cr[3];
        float Cv[16] = {c0.x, c0.y, c0.z, c0.w, c1.x, c1.y, c1.z, c1.w,
                        c2.x, c2.y, c2.z, c2.w, c3.x, c3.y, c3.z, c3.w};
        float y = 0.0f;
#pragma unroll
        for (int n = 0; n < NN; ++n) {
            float dA = exp2f(dlt * A2[n]);
            h[n] = fmaf(dA, h[n], du * Bv[n]);
            y = fmaf(h[n], Cv[n], y);
        }
        y = fmaf(dval, uv, y);
        yp[(size_t)l * NCH] = y;
    }
}

// ------------------------------------------- cross-merge from [bk][l][c]
__global__ __launch_bounds__(256) void k_merge(const float* __restrict__ ybuf,
                                               float* __restrict__ out) {
    int b = blockIdx.x / NH;
    int hh = blockIdx.x % NH;
    __shared__ float tile[NW * 193];
    const float* Y0 = ybuf + (size_t)(b * NK + 0) * NL * NCH;
    const float* Y1 = ybuf + (size_t)(b * NK + 1) * NL * NCH;
    const float* Y2 = ybuf + (size_t)(b * NK + 2) * NL * NCH;
    const float* Y3 = ybuf + (size_t)(b * NK + 3) * NL * NCH;
    for (int i = threadIdx.x; i < NW * NCH; i += 256) {
        int w = i / NCH, c = i % NCH;
        int hw = hh * NW + w;
        int wh = w * NH + hh;
        float v = Y0[(size_t)hw * NCH + c]
                + Y2[(size_t)(NL - 1 - hw) * NCH + c]
                + Y1[(size_t)wh * NCH + c]
                + Y3[(size_t)(NL - 1 - wh) * NCH + c];
        tile[w * 193 + c] = v;
    }
    __syncthreads();
    for (int i = threadIdx.x; i < NW * NCH; i += 256) {
        int c = i / NW, w = i % NW;
        out[((size_t)(b * NCH + c)) * NL + hh * NW + w] = tile[w * 193 + c];
    }
}

extern "C" void kernel_launch(void* const* d_in, const int* in_sizes, int n_in,
                              void* d_out, int out_size, void* d_ws, size_t ws_size,
                              hipStream_t stream) {
    const float* x      = (const float*)d_in[0];
    const float* xpw    = (const float*)d_in[1];
    const float* dtw    = (const float*)d_in[2];
    const float* A_logs = (const float*)d_in[3];
    const float* Ds     = (const float*)d_in[4];
    const float* dtb    = (const float*)d_in[5];
    float* out = (float*)d_out;

    float* ws = (float*)d_ws;
    float* xT    = ws;
    float* ut0   = xT + SZ_XT;
    float* BC    = ut0 + SZ_UT0;
    float* delta = BC + SZ_BC;
    float* ybuf  = delta + SZ_DELTA;
    float* PubP  = ybuf + SZ_YBUF;
    float* PubH  = PubP + SZ_PUB;
    float* PubI  = PubH + SZ_PUB;
    unsigned* flags = (unsigned*)(PubI + SZ_PUB);

    k_prep<<<NB * NCH + NB * 36, 256, 0, stream>>>(x, xT, ut0, flags);
    k_proj<<<NB * NK * 36, 192, 0, stream>>>(x, xT, xpw, dtw, dtb, BC, delta);
    k_scan<<<NBLK, 192, 0, stream>>>(ut0, BC, delta, A_logs, Ds,
                                     PubP, PubH, PubI, flags, ybuf);
    k_merge<<<NB * NH, 256, 0, stream>>>(ybuf, out);
}

// Round 4
// 210.250 us; speedup vs baseline: 3.2397x; 3.2397x over previous
//
#include <hip/hip_runtime.h>
#include <math.h>

#define NB 2
#define NCH 192
#define NH 48
#define NW 48
#define NL 2304
#define NK 4
#define NN 16
#define NR 12
#define ND 44
#define NDP 48
#define NCHUNK 192
#define CLEN 12     // NL / NCHUNK
#define NBLK (NB * NK * NCHUNK)   // 1536 scan blocks

// workspace float sizes
#define SZ_XT    (NB * NCH * NL)                 // 884736
#define SZ_UT0   (NB * NL * NCH)                 // 884736
#define SZ_BC    (NB * NK * NL * 32)             // 589824
#define SZ_DELTA (NB * NK * NL * NCH)            // 3538944
#define SZ_YBUF  (NB * NK * NL * NCH)            // 3538944
#define SZ_P     (NB * NK * NCHUNK * NCH * NN)   // 4718592

// --------------------------------------------- prep: xT + ut0 (one launch)
__global__ __launch_bounds__(256) void k_prep(const float* __restrict__ x,
                                              float* __restrict__ xT,
                                              float* __restrict__ ut0) {
    __shared__ float tile[64 * 193];
    int bid = blockIdx.x;
    if (bid < NB * NCH) {
        // xT[b][c][w*48+h] = x[b][c][h*48+w]
        const float* src = x + (size_t)bid * NL;
        float* dst = xT + (size_t)bid * NL;
        for (int i = threadIdx.x; i < NL; i += 256) {
            int h = i / NW, w = i % NW;
            tile[w * 49 + h] = src[i];
        }
        __syncthreads();
        for (int i = threadIdx.x; i < NL; i += 256) {
            dst[i] = tile[i + i / NH];
        }
    } else {
        // ut0[b][l][c] = x[b][c][l]
        int t = bid - NB * NCH;                // 0..71
        int b = t / 36, lt = t % 36;
        int l0 = lt * 64;
        const float* bx = x + (size_t)b * NCH * NL;
        for (int i = threadIdx.x; i < NCH * 64; i += 256) {
            int c = i >> 6, j = i & 63;        // coalesced read along l
            tile[j * 193 + c] = bx[(size_t)c * NL + l0 + j];
        }
        __syncthreads();
        float* bo = ut0 + (size_t)b * NL * NCH;
        for (int i = threadIdx.x; i < NCH * 64; i += 256) {
            int j = i / NCH, c = i % NCH;      // coalesced write along c
            bo[(size_t)(l0 + j) * NCH + c] = tile[j * 193 + c];
        }
    }
}

// --------------------- proj: BC[bk][l][32] (B then C) + delta[bk][l][c] fused
__global__ __launch_bounds__(192) void k_proj(const float* __restrict__ x,
                                              const float* __restrict__ xT,
                                              const float* __restrict__ xpw,
                                              const float* __restrict__ dtw,
                                              const float* __restrict__ dt_bias,
                                              float* __restrict__ BC,
                                              float* __restrict__ delta) {
    int bid = blockIdx.x;                      // 8 * 36
    int bk = bid / 36;
    int lt0 = (bid % 36) * 64;
    int b = bk >> 2, k = bk & 3;
    int tid = threadIdx.x;
    int lt = tid & 15;
    int dt = tid >> 4;                         // 0..11
    __shared__ float WT[NCH * NDP];            // 36.9 KB
    __shared__ float XS[48 * 64];              // 12.3 KB
    __shared__ float DT[64 * NR];              // 3.0 KB
    for (int i = tid; i < NCH * NDP; i += 192) {
        int c = i / NDP, d = i % NDP;
        WT[i] = (d < ND) ? xpw[((size_t)k * ND + d) * NCH + c] : 0.0f;
    }
    const float* bx = ((k & 1) ? xT : x) + (size_t)b * NCH * NL;
    bool rev = (k >= 2);
    float acc[16];
#pragma unroll
    for (int i = 0; i < 16; ++i) acc[i] = 0.0f;
    for (int ch = 0; ch < 4; ++ch) {
        int c0 = ch * 48;
        __syncthreads();
        for (int i = tid; i < 48 * 64; i += 192) {
            int cc = i >> 6, j = i & 63;
            int gl = lt0 + j;
            if (rev) gl = NL - 1 - gl;
            XS[i] = bx[(size_t)(c0 + cc) * NL + gl];
        }
        __syncthreads();
#pragma unroll 4
        for (int cc = 0; cc < 48; ++cc) {
            float4 wv = *(const float4*)&WT[(c0 + cc) * NDP + dt * 4];
            float4 xv = *(const float4*)&XS[cc * 64 + lt * 4];
            float xa[4] = {xv.x, xv.y, xv.z, xv.w};
            float wa[4] = {wv.x, wv.y, wv.z, wv.w};
#pragma unroll
            for (int li = 0; li < 4; ++li)
#pragma unroll
                for (int di = 0; di < 4; ++di)
                    acc[li * 4 + di] = fmaf(xa[li], wa[di], acc[li * 4 + di]);
        }
    }
    // d 0..11 -> DT (LDS only); d 12..43 -> BC global (compacted by -12)
    if (dt < 3) {
#pragma unroll
        for (int li = 0; li < 4; ++li) {
            float4 o = make_float4(acc[li * 4 + 0], acc[li * 4 + 1],
                                   acc[li * 4 + 2], acc[li * 4 + 3]);
            *(float4*)&DT[(lt * 4 + li) * NR + dt * 4] = o;
        }
    } else if (dt < 11) {
#pragma unroll
        for (int li = 0; li < 4; ++li) {
            int l = lt0 + lt * 4 + li;
            float4 o = make_float4(acc[li * 4 + 0], acc[li * 4 + 1],
                                   acc[li * 4 + 2], acc[li * 4 + 3]);
            *(float4*)&BC[((size_t)bk * NL + l) * 32 + (dt * 4 - 12)] = o;
        }
    }
    __syncthreads();
    // delta for this l-tile: c = tid
    int c = tid;
    const float4* wp = (const float4*)(dtw + ((size_t)k * NCH + c) * NR);
    float4 w0 = wp[0], w1 = wp[1], w2 = wp[2];
    float bias = dt_bias[k * NCH + c];
    for (int l = 0; l < 64; ++l) {
        float4 a0 = *(const float4*)&DT[l * NR + 0];
        float4 a1 = *(const float4*)&DT[l * NR + 4];
        float4 a2 = *(const float4*)&DT[l * NR + 8];
        float acc2 = bias;
        acc2 = fmaf(w0.x, a0.x, acc2); acc2 = fmaf(w0.y, a0.y, acc2);
        acc2 = fmaf(w0.z, a0.z, acc2); acc2 = fmaf(w0.w, a0.w, acc2);
        acc2 = fmaf(w1.x, a1.x, acc2); acc2 = fmaf(w1.y, a1.y, acc2);
        acc2 = fmaf(w1.z, a1.z, acc2); acc2 = fmaf(w1.w, a1.w, acc2);
        acc2 = fmaf(w2.x, a2.x, acc2); acc2 = fmaf(w2.y, a2.y, acc2);
        acc2 = fmaf(w2.z, a2.z, acc2); acc2 = fmaf(w2.w, a2.w, acc2);
        float sp = fmaxf(acc2, 0.0f) + log1pf(expf(-fabsf(acc2)));
        delta[((size_t)bk * NL + lt0 + l) * NCH + c] = sp;
    }
}

__device__ __forceinline__ int u_row(int k, int l) {
    int pos = (k >= 2) ? (NL - 1 - l) : l;
    if (k & 1) pos = (pos % 48) * 48 + (pos / 48);
    return pos;
}

// ---------------------------------------------------- scan pass 1 (per-chunk)
__global__ __launch_bounds__(192) void k_s1(const float* __restrict__ ut0,
                                            const float* __restrict__ BC,
                                            const float* __restrict__ delta,
                                            const float* __restrict__ A_logs,
                                            float* __restrict__ Pbuf,
                                            float* __restrict__ Hend) {
    int bid = blockIdx.x;
    int bk = bid / NCHUNK;
    int ch = bid % NCHUNK;
    int b = bk >> 2, k = bk & 3;
    int c = threadIdx.x;
    float A2[NN];
    {
        const float4* ap = (const float4*)(A_logs + ((size_t)(k * NCH + c)) * NN);
        float4 a0 = ap[0], a1 = ap[1], a2 = ap[2], a3 = ap[3];
        float t[16] = {a0.x, a0.y, a0.z, a0.w, a1.x, a1.y, a1.z, a1.w,
                       a2.x, a2.y, a2.z, a2.w, a3.x, a3.y, a3.z, a3.w};
#pragma unroll
        for (int n = 0; n < NN; ++n) A2[n] = -expf(t[n]) * 1.44269504f;
    }
    float h[NN];
#pragma unroll
    for (int n = 0; n < NN; ++n) h[n] = 0.0f;
    float S = 0.0f;
    const float* dp = delta + (size_t)bk * NL * NCH + c;
    const float* up = ut0 + (size_t)b * NL * NCH + c;
    int l0 = ch * CLEN;
#pragma unroll
    for (int i = 0; i < CLEN; ++i) {
        int l = l0 + i;
        float dlt = dp[(size_t)l * NCH];
        float uv = up[(size_t)u_row(k, l) * NCH];
        float du = dlt * uv;
        S += dlt;
        const float4* br = (const float4*)(BC + ((size_t)bk * NL + l) * 32);
        float4 b0 = br[0], b1 = br[1], b2 = br[2], b3 = br[3];
        float Bv[16] = {b0.x, b0.y, b0.z, b0.w, b1.x, b1.y, b1.z, b1.w,
                        b2.x, b2.y, b2.z, b2.w, b3.x, b3.y, b3.z, b3.w};
#pragma unroll
        for (int n = 0; n < NN; ++n) {
            float dA = exp2f(dlt * A2[n]);
            h[n] = fmaf(dA, h[n], du * Bv[n]);
        }
    }
    size_t ob = (((size_t)bk * NCHUNK + ch) * NCH + c) * NN;
#pragma unroll
    for (int q = 0; q < 4; ++q) {
        float4 hv = make_float4(h[q * 4], h[q * 4 + 1], h[q * 4 + 2], h[q * 4 + 3]);
        *(float4*)&Hend[ob + q * 4] = hv;
        float4 pv = make_float4(exp2f(S * A2[q * 4 + 0]), exp2f(S * A2[q * 4 + 1]),
                                exp2f(S * A2[q * 4 + 2]), exp2f(S * A2[q * 4 + 3]));
        *(float4*)&Pbuf[ob + q * 4] = pv;
    }
}

// ------------------------------------------- scan pass 2 (chunk prefix, in place)
// After this kernel Hend[j] holds the INCOMING state for chunk j.
__global__ __launch_bounds__(256) void k_s2(const float* __restrict__ Pbuf,
                                            float* __restrict__ Hend) {
    int g = blockIdx.x * 256 + threadIdx.x;    // 0..24575
    int bk = g / (NCH * NN);
    int cn = g % (NCH * NN);
    float h = 0.0f;
    for (int j = 0; j < NCHUNK; ++j) {
        size_t idx = ((size_t)bk * NCHUNK + j) * (NCH * NN) + cn;
        float P = Pbuf[idx];
        float E = Hend[idx];
        Hend[idx] = h;
        h = fmaf(P, h, E);
    }
}

// ---------------------------------------------------- scan pass 3 (emit y)
// y stored as ybuf[bk][l][c] (coalesced)
__global__ __launch_bounds__(192) void k_s3(const float* __restrict__ ut0,
                                            const float* __restrict__ BC,
                                            const float* __restrict__ delta,
                                            const float* __restrict__ A_logs,
                                            const float* __restrict__ Ds,
                                            const float* __restrict__ Hin,
                                            float* __restrict__ ybuf) {
    int bid = blockIdx.x;
    int bk = bid / NCHUNK;
    int ch = bid % NCHUNK;
    int b = bk >> 2, k = bk & 3;
    int c = threadIdx.x;
    float A2[NN];
    {
        const float4* ap = (const float4*)(A_logs + ((size_t)(k * NCH + c)) * NN);
        float4 a0 = ap[0], a1 = ap[1], a2 = ap[2], a3 = ap[3];
        float t[16] = {a0.x, a0.y, a0.z, a0.w, a1.x, a1.y, a1.z, a1.w,
                       a2.x, a2.y, a2.z, a2.w, a3.x, a3.y, a3.z, a3.w};
#pragma unroll
        for (int n = 0; n < NN; ++n) A2[n] = -expf(t[n]) * 1.44269504f;
    }
    float h[NN];
    size_t ob = (((size_t)bk * NCHUNK + ch) * NCH + c) * NN;
    {
        const float4* hp = (const float4*)(Hin + ob);
        float4 h0 = hp[0], h1 = hp[1], h2 = hp[2], h3 = hp[3];
        float t[16] = {h0.x, h0.y, h0.z, h0.w, h1.x, h1.y, h1.z, h1.w,
                       h2.x, h2.y, h2.z, h2.w, h3.x, h3.y, h3.z, h3.w};
#pragma unroll
        for (int n = 0; n < NN; ++n) h[n] = t[n];
    }
    float dval = Ds[k * NCH + c];
    const float* dp = delta + (size_t)bk * NL * NCH + c;
    const float* up = ut0 + (size_t)b * NL * NCH + c;
    float* yp = ybuf + (size_t)bk * NL * NCH + c;
    int l0 = ch * CLEN;
#pragma unroll
    for (int i = 0; i < CLEN; ++i) {
        int l = l0 + i;
        float dlt = dp[(size_t)l * NCH];
        float uv = up[(size_t)u_row(k, l) * NCH];
        float du = dlt * uv;
        const float* row = BC + ((size_t)bk * NL + l) * 32;
        const float4* br = (const float4*)row;
        float4 b0 = br[0], b1 = br[1], b2 = br[2], b3 = br[3];
        float Bv[16] = {b0.x, b0.y, b0.z, b0.w, b1.x, b1.y, b1.z, b1.w,
                        b2.x, b2.y, b2.z, b2.w, b3.x, b3.y, b3.z, b3.w};
        const float4* cr = (const float4*)(row + NN);
        float4 c0 = cr[0], c1 = cr[1], c2 = cr[2], c3 = cr[3];
        float Cv[16] = {c0.x, c0.y, c0.z, c0.w, c1.x, c1.y, c1.z, c1.w,
                        c2.x, c2.y, c2.z, c2.w, c3.x, c3.y, c3.z, c3.w};
        float y = 0.0f;
#pragma unroll
        for (int n = 0; n < NN; ++n) {
            float dA = exp2f(dlt * A2[n]);
            h[n] = fmaf(dA, h[n], du * Bv[n]);
            y = fmaf(h[n], Cv[n], y);
        }
        y = fmaf(dval, uv, y);
        yp[(size_t)l * NCH] = y;
    }
}

// ------------------------------------------- cross-merge from [bk][l][c]
__global__ __launch_bounds__(256) void k_merge(const float* __restrict__ ybuf,
                                               float* __restrict__ out) {
    int b = blockIdx.x / NH;
    int hh = blockIdx.x % NH;
    __shared__ float tile[NW * 193];
    const float* Y0 = ybuf + (size_t)(b * NK + 0) * NL * NCH;
    const float* Y1 = ybuf + (size_t)(b * NK + 1) * NL * NCH;
    const float* Y2 = ybuf + (size_t)(b * NK + 2) * NL * NCH;
    const float* Y3 = ybuf + (size_t)(b * NK + 3) * NL * NCH;
    for (int i = threadIdx.x; i < NW * NCH; i += 256) {
        int w = i / NCH, c = i % NCH;
        int hw = hh * NW + w;
        int wh = w * NH + hh;
        float v = Y0[(size_t)hw * NCH + c]
                + Y2[(size_t)(NL - 1 - hw) * NCH + c]
                + Y1[(size_t)wh * NCH + c]
                + Y3[(size_t)(NL - 1 - wh) * NCH + c];
        tile[w * 193 + c] = v;
    }
    __syncthreads();
    for (int i = threadIdx.x; i < NW * NCH; i += 256) {
        int c = i / NW, w = i % NW;
        out[((size_t)(b * NCH + c)) * NL + hh * NW + w] = tile[w * 193 + c];
    }
}

extern "C" void kernel_launch(void* const* d_in, const int* in_sizes, int n_in,
                              void* d_out, int out_size, void* d_ws, size_t ws_size,
                              hipStream_t stream) {
    const float* x      = (const float*)d_in[0];
    const float* xpw    = (const float*)d_in[1];
    const float* dtw    = (const float*)d_in[2];
    const float* A_logs = (const float*)d_in[3];
    const float* Ds     = (const float*)d_in[4];
    const float* dtb    = (const float*)d_in[5];
    float* out = (float*)d_out;

    float* ws = (float*)d_ws;
    float* xT    = ws;
    float* ut0   = xT + SZ_XT;
    float* BC    = ut0 + SZ_UT0;
    float* delta = BC + SZ_BC;
    float* ybuf  = delta + SZ_DELTA;
    float* Pbuf  = ybuf + SZ_YBUF;
    float* Hend  = Pbuf + SZ_P;    // after k_s2 holds Hin (in-place)

    k_prep<<<NB * NCH + NB * 36, 256, 0, stream>>>(x, xT, ut0);
    k_proj<<<NB * NK * 36, 192, 0, stream>>>(x, xT, xpw, dtw, dtb, BC, delta);
    k_s1<<<NBLK, 192, 0, stream>>>(ut0, BC, delta, A_logs, Pbuf, Hend);
    k_s2<<<(NB * NK * NCH * NN) / 256, 256, 0, stream>>>(Pbuf, Hend);
    k_s3<<<NBLK, 192, 0, stream>>>(ut0, BC, delta, A_logs, Ds, Hend, ybuf);
    k_merge<<<NB * NH, 256, 0, stream>>>(ybuf, out);
}

// Round 5
// 206.908 us; speedup vs baseline: 3.2920x; 1.0162x over previous
//
#include <hip/hip_runtime.h>
#include <math.h>

#define NB 2
#define NCH 192
#define NH 48
#define NW 48
#define NL 2304
#define NK 4
#define NN 16
#define NR 12
#define ND 44
#define NDP 48
#define NCHUNK 144
#define CLEN 16                     // NL / NCHUNK
#define LTILE 32
#define NLT (NL / LTILE)            // 72
#define NBLK3 (NB * NK * NCHUNK)    // 1152 scan blocks

// workspace float sizes
#define SZ_XT    (NB * NCH * NL)                 // 884736
#define SZ_UT0   (NB * NL * NCH)                 // 884736
#define SZ_BC    (NB * NK * NL * 32)             // 589824
#define SZ_DELTA (NB * NK * NL * NCH)            // 3538944
#define SZ_YBUF  (NB * NK * NL * NCH)            // 3538944
#define SZ_HEND  (NB * NK * NCHUNK * NCH * NN)   // 3538944
#define SZ_S     (NB * NK * NCHUNK * NCH)        // 221184

// --------------------------------------------- prep: xT + ut0 (one launch)
__global__ __launch_bounds__(256) void k_prep(const float* __restrict__ x,
                                              float* __restrict__ xT,
                                              float* __restrict__ ut0) {
    __shared__ float tile[64 * 193];
    int bid = blockIdx.x;
    if (bid < NB * NCH) {
        // xT[b][c][w*48+h] = x[b][c][h*48+w]
        const float* src = x + (size_t)bid * NL;
        float* dst = xT + (size_t)bid * NL;
        for (int i = threadIdx.x; i < NL; i += 256) {
            int h = i / NW, w = i % NW;
            tile[w * 49 + h] = src[i];
        }
        __syncthreads();
        for (int i = threadIdx.x; i < NL; i += 256) {
            dst[i] = tile[i + i / NH];
        }
    } else {
        // ut0[b][l][c] = x[b][c][l]
        int t = bid - NB * NCH;                // 0..71
        int b = t / 36, lt = t % 36;
        int l0 = lt * 64;
        const float* bx = x + (size_t)b * NCH * NL;
        for (int i = threadIdx.x; i < NCH * 64; i += 256) {
            int c = i >> 6, j = i & 63;        // coalesced read along l
            tile[j * 193 + c] = bx[(size_t)c * NL + l0 + j];
        }
        __syncthreads();
        float* bo = ut0 + (size_t)b * NL * NCH;
        for (int i = threadIdx.x; i < NCH * 64; i += 256) {
            int j = i / NCH, c = i % NCH;      // coalesced write along c
            bo[(size_t)(l0 + j) * NCH + c] = tile[j * 193 + c];
        }
    }
}

__device__ __forceinline__ int u_row(int k, int l) {
    int pos = (k >= 2) ? (NL - 1 - l) : l;
    if (k & 1) pos = (pos % 48) * 48 + (pos / 48);
    return pos;
}

// ---- fused proj + delta + chunk-local scan (s1).
// Outputs: BC[bk][l][32], delta[bk][l][c], Hend[bk][ch][c][16], Sbuf[bk][ch][c]
__global__ __launch_bounds__(192) void k_projscan(const float* __restrict__ x,
                                                  const float* __restrict__ xT,
                                                  const float* __restrict__ xpw,
                                                  const float* __restrict__ dtw,
                                                  const float* __restrict__ dt_bias,
                                                  const float* __restrict__ A_logs,
                                                  const float* __restrict__ ut0,
                                                  float* __restrict__ BC,
                                                  float* __restrict__ delta,
                                                  float* __restrict__ Hend,
                                                  float* __restrict__ Sbuf) {
    int bid = blockIdx.x;                      // 8 * 72
    int bk = bid / NLT;
    int lt0 = (bid % NLT) * LTILE;
    int b = bk >> 2, k = bk & 3;
    int tid = threadIdx.x;
    int lt = tid & 7;                          // 8 l-groups of 4
    int dt = tid >> 3;                         // 0..23, 2 d's each
    __shared__ float WT[NCH * NDP];            // [c][d]  36.9 KB
    __shared__ float XS[48 * LTILE];           // [cc][l]  6.1 KB
    __shared__ float DT[LTILE * NR];           // dts      1.5 KB
    __shared__ float BL[LTILE * NN];           // B        2.0 KB
    for (int i = tid; i < NCH * NDP; i += 192) {
        int c = i / NDP, d = i % NDP;
        WT[i] = (d < ND) ? xpw[((size_t)k * ND + d) * NCH + c] : 0.0f;
    }
    const float* bx = ((k & 1) ? xT : x) + (size_t)b * NCH * NL;
    bool rev = (k >= 2);
    float acc[4][2];
#pragma unroll
    for (int li = 0; li < 4; ++li) { acc[li][0] = 0.0f; acc[li][1] = 0.0f; }
    for (int ch = 0; ch < 4; ++ch) {
        int c0 = ch * 48;
        __syncthreads();
        for (int i = tid; i < 48 * LTILE; i += 192) {
            int cc = i >> 5, j = i & 31;
            int gl = lt0 + j;
            if (rev) gl = NL - 1 - gl;
            XS[i] = bx[(size_t)(c0 + cc) * NL + gl];
        }
        __syncthreads();
#pragma unroll 6
        for (int cc = 0; cc < 48; ++cc) {
            float4 xv = *(const float4*)&XS[cc * LTILE + lt * 4];
            float2 wv = *(const float2*)&WT[(c0 + cc) * NDP + dt * 2];
            float xa[4] = {xv.x, xv.y, xv.z, xv.w};
#pragma unroll
            for (int li = 0; li < 4; ++li) {
                acc[li][0] = fmaf(xa[li], wv.x, acc[li][0]);
                acc[li][1] = fmaf(xa[li], wv.y, acc[li][1]);
            }
        }
    }
    // scatter GEMM outputs: d = dt*2, dt*2+1 (never straddles 12/28/44)
    int d0 = dt * 2;
#pragma unroll
    for (int li = 0; li < 4; ++li) {
        int l = lt * 4 + li;                   // within tile
        if (d0 < NR) {
            DT[l * NR + d0] = acc[li][0];
            DT[l * NR + d0 + 1] = acc[li][1];
        } else if (d0 < ND) {
            if (d0 < NR + NN) {
                BL[l * NN + (d0 - NR)] = acc[li][0];
                BL[l * NN + (d0 - NR) + 1] = acc[li][1];
            }
            *(float2*)&BC[((size_t)bk * NL + lt0 + l) * 32 + (d0 - NR)] =
                make_float2(acc[li][0], acc[li][1]);
        }
    }
    __syncthreads();
    // tail: thread c = tid handles delta + chunk-local scan for this l-tile
    int c = tid;
    float A2[NN];
    {
        const float4* ap = (const float4*)(A_logs + ((size_t)(k * NCH + c)) * NN);
        float4 a0 = ap[0], a1 = ap[1], a2 = ap[2], a3 = ap[3];
        float t[16] = {a0.x, a0.y, a0.z, a0.w, a1.x, a1.y, a1.z, a1.w,
                       a2.x, a2.y, a2.z, a2.w, a3.x, a3.y, a3.z, a3.w};
#pragma unroll
        for (int n = 0; n < NN; ++n) A2[n] = -expf(t[n]) * 1.44269504f;
    }
    const float4* wp = (const float4*)(dtw + ((size_t)k * NCH + c) * NR);
    float4 w0 = wp[0], w1 = wp[1], w2 = wp[2];
    float bias = dt_bias[k * NCH + c];
    const float* up = ut0 + (size_t)b * NL * NCH + c;
    float* dlp = delta + (size_t)bk * NL * NCH + c;
    for (int half = 0; half < 2; ++half) {
        float h[NN];
#pragma unroll
        for (int n = 0; n < NN; ++n) h[n] = 0.0f;
        float S = 0.0f;
#pragma unroll 4
        for (int i2 = 0; i2 < CLEN; ++i2) {
            int i = half * CLEN + i2;
            int l = lt0 + i;
            float4 a0 = *(const float4*)&DT[i * NR + 0];
            float4 a1 = *(const float4*)&DT[i * NR + 4];
            float4 a2 = *(const float4*)&DT[i * NR + 8];
            float acc2 = bias;
            acc2 = fmaf(w0.x, a0.x, acc2); acc2 = fmaf(w0.y, a0.y, acc2);
            acc2 = fmaf(w0.z, a0.z, acc2); acc2 = fmaf(w0.w, a0.w, acc2);
            acc2 = fmaf(w1.x, a1.x, acc2); acc2 = fmaf(w1.y, a1.y, acc2);
            acc2 = fmaf(w1.z, a1.z, acc2); acc2 = fmaf(w1.w, a1.w, acc2);
            acc2 = fmaf(w2.x, a2.x, acc2); acc2 = fmaf(w2.y, a2.y, acc2);
            acc2 = fmaf(w2.z, a2.z, acc2); acc2 = fmaf(w2.w, a2.w, acc2);
            float sp = fmaxf(acc2, 0.0f) + log1pf(expf(-fabsf(acc2)));
            dlp[(size_t)l * NCH] = sp;
            float uv = up[(size_t)u_row(k, l) * NCH];
            float du = sp * uv;
            S += sp;
            const float4* br = (const float4*)&BL[i * NN];
            float4 b0 = br[0], b1 = br[1], b2 = br[2], b3 = br[3];
            float Bv[16] = {b0.x, b0.y, b0.z, b0.w, b1.x, b1.y, b1.z, b1.w,
                            b2.x, b2.y, b2.z, b2.w, b3.x, b3.y, b3.z, b3.w};
#pragma unroll
            for (int n = 0; n < NN; ++n) {
                float dA = exp2f(sp * A2[n]);
                h[n] = fmaf(dA, h[n], du * Bv[n]);
            }
        }
        int chk = lt0 / CLEN + half;
        size_t ob = (((size_t)bk * NCHUNK + chk) * NCH + c) * NN;
#pragma unroll
        for (int q = 0; q < 4; ++q)
            *(float4*)&Hend[ob + q * 4] =
                make_float4(h[q*4], h[q*4+1], h[q*4+2], h[q*4+3]);
        Sbuf[((size_t)bk * NCHUNK + chk) * NCH + c] = S;
    }
}

// ------------- scan pass 2: chunk prefix in place (recomputes P from S)
// After this kernel Hend[j] holds the INCOMING state for chunk j.
__global__ __launch_bounds__(256) void k_s2(const float* __restrict__ Sbuf,
                                            const float* __restrict__ A_logs,
                                            float* __restrict__ Hend) {
    int g = blockIdx.x * 256 + threadIdx.x;    // 0..24575
    int bk = g / (NCH * NN);
    int cn = g % (NCH * NN);
    int c = cn / NN, n = cn % NN;
    int k = bk & 3;
    float A2 = -expf(A_logs[((size_t)(k * NCH + c)) * NN + n]) * 1.44269504f;
    float h = 0.0f;
    for (int j = 0; j < NCHUNK; ++j) {
        float S = Sbuf[((size_t)bk * NCHUNK + j) * NCH + c];
        size_t idx = (((size_t)bk * NCHUNK + j) * NCH + c) * NN + n;
        float E = Hend[idx];
        float P = exp2f(S * A2);
        Hend[idx] = h;
        h = fmaf(P, h, E);
    }
}

// ---------------------------------------------------- scan pass 3 (emit y)
__global__ __launch_bounds__(192) void k_s3(const float* __restrict__ ut0,
                                            const float* __restrict__ BC,
                                            const float* __restrict__ delta,
                                            const float* __restrict__ A_logs,
                                            const float* __restrict__ Ds,
                                            const float* __restrict__ Hin,
                                            float* __restrict__ ybuf) {
    int bid = blockIdx.x;
    int bk = bid / NCHUNK;
    int ch = bid % NCHUNK;
    int b = bk >> 2, k = bk & 3;
    int c = threadIdx.x;
    float A2[NN];
    {
        const float4* ap = (const float4*)(A_logs + ((size_t)(k * NCH + c)) * NN);
        float4 a0 = ap[0], a1 = ap[1], a2 = ap[2], a3 = ap[3];
        float t[16] = {a0.x, a0.y, a0.z, a0.w, a1.x, a1.y, a1.z, a1.w,
                       a2.x, a2.y, a2.z, a2.w, a3.x, a3.y, a3.z, a3.w};
#pragma unroll
        for (int n = 0; n < NN; ++n) A2[n] = -expf(t[n]) * 1.44269504f;
    }
    float h[NN];
    size_t ob = (((size_t)bk * NCHUNK + ch) * NCH + c) * NN;
    {
        const float4* hp = (const float4*)(Hin + ob);
        float4 h0 = hp[0], h1 = hp[1], h2 = hp[2], h3 = hp[3];
        float t[16] = {h0.x, h0.y, h0.z, h0.w, h1.x, h1.y, h1.z, h1.w,
                       h2.x, h2.y, h2.z, h2.w, h3.x, h3.y, h3.z, h3.w};
#pragma unroll
        for (int n = 0; n < NN; ++n) h[n] = t[n];
    }
    float dval = Ds[k * NCH + c];
    const float* dp = delta + (size_t)bk * NL * NCH + c;
    const float* up = ut0 + (size_t)b * NL * NCH + c;
    float* yp = ybuf + (size_t)bk * NL * NCH + c;
    int l0 = ch * CLEN;
#pragma unroll 4
    for (int i = 0; i < CLEN; ++i) {
        int l = l0 + i;
        float dlt = dp[(size_t)l * NCH];
        float uv = up[(size_t)u_row(k, l) * NCH];
        float du = dlt * uv;
        const float* row = BC + ((size_t)bk * NL + l) * 32;
        const float4* br = (const float4*)row;
        float4 b0 = br[0], b1 = br[1], b2 = br[2], b3 = br[3];
        float Bv[16] = {b0.x, b0.y, b0.z, b0.w, b1.x, b1.y, b1.z, b1.w,
                        b2.x, b2.y, b2.z, b2.w, b3.x, b3.y, b3.z, b3.w};
        const float4* cr = (const float4*)(row + NN);
        float4 c0 = cr[0], c1 = cr[1], c2 = cr[2], c3 = cr[3];
        float Cv[16] = {c0.x, c0.y, c0.z, c0.w, c1.x, c1.y, c1.z, c1.w,
                        c2.x, c2.y, c2.z, c2.w, c3.x, c3.y, c3.z, c3.w};
        float y = 0.0f;
#pragma unroll
        for (int n = 0; n < NN; ++n) {
            float dA = exp2f(dlt * A2[n]);
            h[n] = fmaf(dA, h[n], du * Bv[n]);
            y = fmaf(h[n], Cv[n], y);
        }
        y = fmaf(dval, uv, y);
        yp[(size_t)l * NCH] = y;
    }
}

// ------------------------------------------- cross-merge from [bk][l][c]
__global__ __launch_bounds__(256) void k_merge(const float* __restrict__ ybuf,
                                               float* __restrict__ out) {
    int b = blockIdx.x / NH;
    int hh = blockIdx.x % NH;
    __shared__ float tile[NW * 193];
    const float* Y0 = ybuf + (size_t)(b * NK + 0) * NL * NCH;
    const float* Y1 = ybuf + (size_t)(b * NK + 1) * NL * NCH;
    const float* Y2 = ybuf + (size_t)(b * NK + 2) * NL * NCH;
    const float* Y3 = ybuf + (size_t)(b * NK + 3) * NL * NCH;
    for (int i = threadIdx.x; i < NW * NCH; i += 256) {
        int w = i / NCH, c = i % NCH;
        int hw = hh * NW + w;
        int wh = w * NH + hh;
        float v = Y0[(size_t)hw * NCH + c]
                + Y2[(size_t)(NL - 1 - hw) * NCH + c]
                + Y1[(size_t)wh * NCH + c]
                + Y3[(size_t)(NL - 1 - wh) * NCH + c];
        tile[w * 193 + c] = v;
    }
    __syncthreads();
    for (int i = threadIdx.x; i < NW * NCH; i += 256) {
        int c = i / NW, w = i % NW;
        out[((size_t)(b * NCH + c)) * NL + hh * NW + w] = tile[w * 193 + c];
    }
}

extern "C" void kernel_launch(void* const* d_in, const int* in_sizes, int n_in,
                              void* d_out, int out_size, void* d_ws, size_t ws_size,
                              hipStream_t stream) {
    const float* x      = (const float*)d_in[0];
    const float* xpw    = (const float*)d_in[1];
    const float* dtw    = (const float*)d_in[2];
    const float* A_logs = (const float*)d_in[3];
    const float* Ds     = (const float*)d_in[4];
    const float* dtb    = (const float*)d_in[5];
    float* out = (float*)d_out;

    float* ws = (float*)d_ws;
    float* xT    = ws;
    float* ut0   = xT + SZ_XT;
    float* BC    = ut0 + SZ_UT0;
    float* delta = BC + SZ_BC;
    float* ybuf  = delta + SZ_DELTA;
    float* Hend  = ybuf + SZ_YBUF;   // after k_s2 holds Hin (in-place)
    float* Sbuf  = Hend + SZ_HEND;

    k_prep<<<NB * NCH + NB * 36, 256, 0, stream>>>(x, xT, ut0);
    k_projscan<<<NB * NK * NLT, 192, 0, stream>>>(x, xT, xpw, dtw, dtb, A_logs,
                                                  ut0, BC, delta, Hend, Sbuf);
    k_s2<<<(NB * NK * NCH * NN) / 256, 256, 0, stream>>>(Sbuf, A_logs, Hend);
    k_s3<<<NBLK3, 192, 0, stream>>>(ut0, BC, delta, A_logs, Ds, Hend, ybuf);
    k_merge<<<NB * NH, 256, 0, stream>>>(ybuf, out);
}

// Round 6
// 191.689 us; speedup vs baseline: 3.5534x; 1.0794x over previous
//
#include <hip/hip_runtime.h>
#include <math.h>

#define NB 2
#define NCH 192
#define NH 48
#define NW 48
#define NL 2304
#define NK 4
#define NN 16
#define NR 12
#define ND 44
#define NDP 48
#define NCHUNK 144
#define CLEN 16                     // NL / NCHUNK
#define LTILE 16
#define NLT (NL / LTILE)            // 144
#define NBLK3 (NB * NK * NCHUNK)    // 1152 scan blocks

// workspace float sizes
#define SZ_XT    (NB * NCH * NL)                 // 884736
#define SZ_UT0   (NB * NL * NCH)                 // 884736
#define SZ_BC    (NB * NK * NL * 32)             // 589824
#define SZ_DELTA (NB * NK * NL * NCH)            // 3538944
#define SZ_YBUF  (NB * NK * NL * NCH)            // 3538944
#define SZ_HEND  (NB * NK * NCHUNK * NCH * NN)   // 3538944
#define SZ_S     (NB * NK * NCHUNK * NCH)        // 221184

// --------------------------------------------- prep: xT + ut0 (one launch)
__global__ __launch_bounds__(256) void k_prep(const float* __restrict__ x,
                                              float* __restrict__ xT,
                                              float* __restrict__ ut0) {
    __shared__ float tile[64 * 193];
    int bid = blockIdx.x;
    if (bid < NB * NCH) {
        // xT[b][c][w*48+h] = x[b][c][h*48+w]
        const float* src = x + (size_t)bid * NL;
        float* dst = xT + (size_t)bid * NL;
        for (int i = threadIdx.x; i < NL; i += 256) {
            int h = i / NW, w = i % NW;
            tile[w * 49 + h] = src[i];
        }
        __syncthreads();
        for (int i = threadIdx.x; i < NL; i += 256) {
            dst[i] = tile[i + i / NH];
        }
    } else {
        // ut0[b][l][c] = x[b][c][l]
        int t = bid - NB * NCH;                // 0..71
        int b = t / 36, lt = t % 36;
        int l0 = lt * 64;
        const float* bx = x + (size_t)b * NCH * NL;
        for (int i = threadIdx.x; i < NCH * 64; i += 256) {
            int c = i >> 6, j = i & 63;        // coalesced read along l
            tile[j * 193 + c] = bx[(size_t)c * NL + l0 + j];
        }
        __syncthreads();
        float* bo = ut0 + (size_t)b * NL * NCH;
        for (int i = threadIdx.x; i < NCH * 64; i += 256) {
            int j = i / NCH, c = i % NCH;      // coalesced write along c
            bo[(size_t)(l0 + j) * NCH + c] = tile[j * 193 + c];
        }
    }
}

__device__ __forceinline__ int u_row(int k, int l) {
    int pos = (k >= 2) ? (NL - 1 - l) : l;
    if (k & 1) pos = (pos % 48) * 48 + (pos / 48);
    return pos;
}

// ---- fused proj + delta + chunk-local scan (s1). One chunk (16 l) per block.
// Outputs: BC[bk][l][32], delta[bk][l][c], Hend[bk][ch][c][16], Sbuf[bk][ch][c]
__global__ __launch_bounds__(192) void k_projscan(const float* __restrict__ x,
                                                  const float* __restrict__ xT,
                                                  const float* __restrict__ xpw,
                                                  const float* __restrict__ dtw,
                                                  const float* __restrict__ dt_bias,
                                                  const float* __restrict__ A_logs,
                                                  const float* __restrict__ ut0,
                                                  float* __restrict__ BC,
                                                  float* __restrict__ delta,
                                                  float* __restrict__ Hend,
                                                  float* __restrict__ Sbuf) {
    int bid = blockIdx.x;                      // 8 * 144
    int bk = bid / NLT;
    int chk = bid % NLT;
    int lt0 = chk * LTILE;
    int b = bk >> 2, k = bk & 3;
    int tid = threadIdx.x;
    int lt = tid / ND;                         // 0..3 (l-group), tid<176
    int dt = tid % ND;                         // 0..43
    __shared__ float WL[48 * 45];              // [cc][d] pad 45  8.6 KB
    __shared__ float XS[48 * LTILE];           // [cc][l]         3.0 KB
    __shared__ float DT[LTILE * NR];           // dts             0.8 KB
    __shared__ float BL[LTILE * NN];           // B               1.0 KB
    const float* bx = ((k & 1) ? xT : x) + (size_t)b * NCH * NL;
    bool rev = (k >= 2);
    float acc[4] = {0.0f, 0.0f, 0.0f, 0.0f};
    for (int ch = 0; ch < 4; ++ch) {
        int c0 = ch * 48;
        __syncthreads();
        // stage W chunk: WL[cc][d] = xpw[k][d][c0+cc], coalesced along cc
        for (int i = tid; i < 48 * ND; i += 192) {
            int d = i / 48, cc = i % 48;
            WL[cc * 45 + d] = xpw[((size_t)k * ND + d) * NCH + c0 + cc];
        }
        // stage X chunk: XS[cc][j], coalesced along l
        for (int i = tid; i < 48 * LTILE; i += 192) {
            int cc = i >> 4, j = i & 15;
            int gl = lt0 + j;
            if (rev) gl = NL - 1 - gl;
            XS[i] = bx[(size_t)(c0 + cc) * NL + gl];
        }
        __syncthreads();
        if (tid < 4 * ND) {
#pragma unroll 8
            for (int cc = 0; cc < 48; ++cc) {
                float4 xv = *(const float4*)&XS[cc * LTILE + lt * 4];
                float wv = WL[cc * 45 + dt];
                acc[0] = fmaf(xv.x, wv, acc[0]);
                acc[1] = fmaf(xv.y, wv, acc[1]);
                acc[2] = fmaf(xv.z, wv, acc[2]);
                acc[3] = fmaf(xv.w, wv, acc[3]);
            }
        }
    }
    __syncthreads();                           // protect WL/XS reuse windows
    if (tid < 4 * ND) {
#pragma unroll
        for (int li = 0; li < 4; ++li) {
            int l = lt * 4 + li;               // within tile
            if (dt < NR) {
                DT[l * NR + dt] = acc[li];
            } else {
                if (dt < NR + NN) BL[l * NN + (dt - NR)] = acc[li];
                BC[((size_t)bk * NL + lt0 + l) * 32 + (dt - NR)] = acc[li];
            }
        }
    }
    __syncthreads();
    // tail: thread c = tid does delta + chunk-local scan over CLEN=16
    int c = tid;
    float A2[NN];
    {
        const float4* ap = (const float4*)(A_logs + ((size_t)(k * NCH + c)) * NN);
        float4 a0 = ap[0], a1 = ap[1], a2 = ap[2], a3 = ap[3];
        float t[16] = {a0.x, a0.y, a0.z, a0.w, a1.x, a1.y, a1.z, a1.w,
                       a2.x, a2.y, a2.z, a2.w, a3.x, a3.y, a3.z, a3.w};
#pragma unroll
        for (int n = 0; n < NN; ++n) A2[n] = -expf(t[n]) * 1.44269504f;
    }
    const float4* wp = (const float4*)(dtw + ((size_t)k * NCH + c) * NR);
    float4 w0 = wp[0], w1 = wp[1], w2 = wp[2];
    float bias = dt_bias[k * NCH + c];
    const float* up = ut0 + (size_t)b * NL * NCH + c;
    float* dlp = delta + (size_t)bk * NL * NCH + c;
    float h[NN];
#pragma unroll
    for (int n = 0; n < NN; ++n) h[n] = 0.0f;
    float S = 0.0f;
#pragma unroll 4
    for (int i = 0; i < CLEN; ++i) {
        int l = lt0 + i;
        float4 a0 = *(const float4*)&DT[i * NR + 0];
        float4 a1 = *(const float4*)&DT[i * NR + 4];
        float4 a2 = *(const float4*)&DT[i * NR + 8];
        float acc2 = bias;
        acc2 = fmaf(w0.x, a0.x, acc2); acc2 = fmaf(w0.y, a0.y, acc2);
        acc2 = fmaf(w0.z, a0.z, acc2); acc2 = fmaf(w0.w, a0.w, acc2);
        acc2 = fmaf(w1.x, a1.x, acc2); acc2 = fmaf(w1.y, a1.y, acc2);
        acc2 = fmaf(w1.z, a1.z, acc2); acc2 = fmaf(w1.w, a1.w, acc2);
        acc2 = fmaf(w2.x, a2.x, acc2); acc2 = fmaf(w2.y, a2.y, acc2);
        acc2 = fmaf(w2.z, a2.z, acc2); acc2 = fmaf(w2.w, a2.w, acc2);
        float sp = fmaxf(acc2, 0.0f) + log1pf(expf(-fabsf(acc2)));
        dlp[(size_t)l * NCH] = sp;
        float uv = up[(size_t)u_row(k, l) * NCH];
        float du = sp * uv;
        S += sp;
        const float4* br = (const float4*)&BL[i * NN];
        float4 b0 = br[0], b1 = br[1], b2 = br[2], b3 = br[3];
        float Bv[16] = {b0.x, b0.y, b0.z, b0.w, b1.x, b1.y, b1.z, b1.w,
                        b2.x, b2.y, b2.z, b2.w, b3.x, b3.y, b3.z, b3.w};
#pragma unroll
        for (int n = 0; n < NN; ++n) {
            float dA = exp2f(sp * A2[n]);
            h[n] = fmaf(dA, h[n], du * Bv[n]);
        }
    }
    size_t ob = (((size_t)bk * NCHUNK + chk) * NCH + c) * NN;
#pragma unroll
    for (int q = 0; q < 4; ++q)
        *(float4*)&Hend[ob + q * 4] =
            make_float4(h[q*4], h[q*4+1], h[q*4+2], h[q*4+3]);
    Sbuf[((size_t)bk * NCHUNK + chk) * NCH + c] = S;
}

// ------------- scan pass 2: chunk prefix in place (recomputes P from S)
// After this kernel Hend[j] holds the INCOMING state for chunk j.
__global__ __launch_bounds__(256) void k_s2(const float* __restrict__ Sbuf,
                                            const float* __restrict__ A_logs,
                                            float* __restrict__ Hend) {
    int g = blockIdx.x * 256 + threadIdx.x;    // 0..24575
    int bk = g / (NCH * NN);
    int cn = g % (NCH * NN);
    int c = cn / NN, n = cn % NN;
    int k = bk & 3;
    float A2 = -expf(A_logs[((size_t)(k * NCH + c)) * NN + n]) * 1.44269504f;
    float h = 0.0f;
    for (int j = 0; j < NCHUNK; ++j) {
        float S = Sbuf[((size_t)bk * NCHUNK + j) * NCH + c];
        size_t idx = (((size_t)bk * NCHUNK + j) * NCH + c) * NN + n;
        float E = Hend[idx];
        float P = exp2f(S * A2);
        Hend[idx] = h;
        h = fmaf(P, h, E);
    }
}

// ---------------------------------------------------- scan pass 3 (emit y)
__global__ __launch_bounds__(192) void k_s3(const float* __restrict__ ut0,
                                            const float* __restrict__ BC,
                                            const float* __restrict__ delta,
                                            const float* __restrict__ A_logs,
                                            const float* __restrict__ Ds,
                                            const float* __restrict__ Hin,
                                            float* __restrict__ ybuf) {
    int bid = blockIdx.x;
    int bk = bid / NCHUNK;
    int ch = bid % NCHUNK;
    int b = bk >> 2, k = bk & 3;
    int c = threadIdx.x;
    float A2[NN];
    {
        const float4* ap = (const float4*)(A_logs + ((size_t)(k * NCH + c)) * NN);
        float4 a0 = ap[0], a1 = ap[1], a2 = ap[2], a3 = ap[3];
        float t[16] = {a0.x, a0.y, a0.z, a0.w, a1.x, a1.y, a1.z, a1.w,
                       a2.x, a2.y, a2.z, a2.w, a3.x, a3.y, a3.z, a3.w};
#pragma unroll
        for (int n = 0; n < NN; ++n) A2[n] = -expf(t[n]) * 1.44269504f;
    }
    float h[NN];
    size_t ob = (((size_t)bk * NCHUNK + ch) * NCH + c) * NN;
    {
        const float4* hp = (const float4*)(Hin + ob);
        float4 h0 = hp[0], h1 = hp[1], h2 = hp[2], h3 = hp[3];
        float t[16] = {h0.x, h0.y, h0.z, h0.w, h1.x, h1.y, h1.z, h1.w,
                       h2.x, h2.y, h2.z, h2.w, h3.x, h3.y, h3.z, h3.w};
#pragma unroll
        for (int n = 0; n < NN; ++n) h[n] = t[n];
    }
    float dval = Ds[k * NCH + c];
    const float* dp = delta + (size_t)bk * NL * NCH + c;
    const float* up = ut0 + (size_t)b * NL * NCH + c;
    float* yp = ybuf + (size_t)bk * NL * NCH + c;
    int l0 = ch * CLEN;
#pragma unroll 4
    for (int i = 0; i < CLEN; ++i) {
        int l = l0 + i;
        float dlt = dp[(size_t)l * NCH];
        float uv = up[(size_t)u_row(k, l) * NCH];
        float du = dlt * uv;
        const float* row = BC + ((size_t)bk * NL + l) * 32;
        const float4* br = (const float4*)row;
        float4 b0 = br[0], b1 = br[1], b2 = br[2], b3 = br[3];
        float Bv[16] = {b0.x, b0.y, b0.z, b0.w, b1.x, b1.y, b1.z, b1.w,
                        b2.x, b2.y, b2.z, b2.w, b3.x, b3.y, b3.z, b3.w};
        const float4* cr = (const float4*)(row + NN);
        float4 c0 = cr[0], c1 = cr[1], c2 = cr[2], c3 = cr[3];
        float Cv[16] = {c0.x, c0.y, c0.z, c0.w, c1.x, c1.y, c1.z, c1.w,
                        c2.x, c2.y, c2.z, c2.w, c3.x, c3.y, c3.z, c3.w};
        float y = 0.0f;
#pragma unroll
        for (int n = 0; n < NN; ++n) {
            float dA = exp2f(dlt * A2[n]);
            h[n] = fmaf(dA, h[n], du * Bv[n]);
            y = fmaf(h[n], Cv[n], y);
        }
        y = fmaf(dval, uv, y);
        yp[(size_t)l * NCH] = y;
    }
}

// ------------------------------------------- cross-merge from [bk][l][c]
__global__ __launch_bounds__(256) void k_merge(const float* __restrict__ ybuf,
                                               float* __restrict__ out) {
    int b = blockIdx.x / NH;
    int hh = blockIdx.x % NH;
    __shared__ float tile[NW * 193];
    const float* Y0 = ybuf + (size_t)(b * NK + 0) * NL * NCH;
    const float* Y1 = ybuf + (size_t)(b * NK + 1) * NL * NCH;
    const float* Y2 = ybuf + (size_t)(b * NK + 2) * NL * NCH;
    const float* Y3 = ybuf + (size_t)(b * NK + 3) * NL * NCH;
    for (int i = threadIdx.x; i < NW * NCH; i += 256) {
        int w = i / NCH, c = i % NCH;
        int hw = hh * NW + w;
        int wh = w * NH + hh;
        float v = Y0[(size_t)hw * NCH + c]
                + Y2[(size_t)(NL - 1 - hw) * NCH + c]
                + Y1[(size_t)wh * NCH + c]
                + Y3[(size_t)(NL - 1 - wh) * NCH + c];
        tile[w * 193 + c] = v;
    }
    __syncthreads();
    for (int i = threadIdx.x; i < NW * NCH; i += 256) {
        int c = i / NW, w = i % NW;
        out[((size_t)(b * NCH + c)) * NL + hh * NW + w] = tile[w * 193 + c];
    }
}

extern "C" void kernel_launch(void* const* d_in, const int* in_sizes, int n_in,
                              void* d_out, int out_size, void* d_ws, size_t ws_size,
                              hipStream_t stream) {
    const float* x      = (const float*)d_in[0];
    const float* xpw    = (const float*)d_in[1];
    const float* dtw    = (const float*)d_in[2];
    const float* A_logs = (const float*)d_in[3];
    const float* Ds     = (const float*)d_in[4];
    const float* dtb    = (const float*)d_in[5];
    float* out = (float*)d_out;

    float* ws = (float*)d_ws;
    float* xT    = ws;
    float* ut0   = xT + SZ_XT;
    float* BC    = ut0 + SZ_UT0;
    float* delta = BC + SZ_BC;
    float* ybuf  = delta + SZ_DELTA;
    float* Hend  = ybuf + SZ_YBUF;   // after k_s2 holds Hin (in-place)
    float* Sbuf  = Hend + SZ_HEND;

    k_prep<<<NB * NCH + NB * 36, 256, 0, stream>>>(x, xT, ut0);
    k_projscan<<<NB * NK * NLT, 192, 0, stream>>>(x, xT, xpw, dtw, dtb, A_logs,
                                                  ut0, BC, delta, Hend, Sbuf);
    k_s2<<<(NB * NK * NCH * NN) / 256, 256, 0, stream>>>(Sbuf, A_logs, Hend);
    k_s3<<<NBLK3, 192, 0, stream>>>(ut0, BC, delta, A_logs, Ds, Hend, ybuf);
    k_merge<<<NB * NH, 256, 0, stream>>>(ybuf, out);
}

// Round 7
// 190.487 us; speedup vs baseline: 3.5758x; 1.0063x over previous
//
#include <hip/hip_runtime.h>
#include <math.h>

#define NB 2
#define NCH 192
#define NH 48
#define NW 48
#define NL 2304
#define NK 4
#define NN 16
#define NR 12
#define ND 44
#define NCHUNK 144
#define CLEN 16                     // NL / NCHUNK
#define LTILE 16
#define NLT (NL / LTILE)            // 144 (== NCHUNK, tile == chunk)

// workspace float sizes
#define SZ_XT    (NB * NCH * NL)                 // 884736
#define SZ_UT0   (NB * NL * NCH)                 // 884736
#define SZ_CB    (NB * NK * NL * NN)             // 294912
#define SZ_CUMS  (NB * NK * NL * NCH)            // 3538944
#define SZ_YBUF  (NB * NK * NL * NCH)            // 3538944
#define SZ_HEND  (NB * NK * NCHUNK * NCH * NN)   // 3538944

// --------------------------------------------- prep: xT + ut0 (one launch)
__global__ __launch_bounds__(256) void k_prep(const float* __restrict__ x,
                                              float* __restrict__ xT,
                                              float* __restrict__ ut0) {
    __shared__ float tile[64 * 193];
    int bid = blockIdx.x;
    if (bid < NB * NCH) {
        // xT[b][c][w*48+h] = x[b][c][h*48+w]
        const float* src = x + (size_t)bid * NL;
        float* dst = xT + (size_t)bid * NL;
        for (int i = threadIdx.x; i < NL; i += 256) {
            int h = i / NW, w = i % NW;
            tile[w * 49 + h] = src[i];
        }
        __syncthreads();
        for (int i = threadIdx.x; i < NL; i += 256) {
            dst[i] = tile[i + i / NH];
        }
    } else {
        // ut0[b][l][c] = x[b][c][l]
        int t = bid - NB * NCH;                // 0..71
        int b = t / 36, lt = t % 36;
        int l0 = lt * 64;
        const float* bx = x + (size_t)b * NCH * NL;
        for (int i = threadIdx.x; i < NCH * 64; i += 256) {
            int c = i >> 6, j = i & 63;        // coalesced read along l
            tile[j * 193 + c] = bx[(size_t)c * NL + l0 + j];
        }
        __syncthreads();
        float* bo = ut0 + (size_t)b * NL * NCH;
        for (int i = threadIdx.x; i < NCH * 64; i += 256) {
            int j = i / NCH, c = i % NCH;      // coalesced write along c
            bo[(size_t)(l0 + j) * NCH + c] = tile[j * 193 + c];
        }
    }
}

__device__ __forceinline__ int u_row(int k, int l) {
    int pos = (k >= 2) ? (NL - 1 - l) : l;
    if (k & 1) pos = (pos % 48) * 48 + (pos / 48);
    return pos;
}

// ---- fused proj + delta + chunk-local scan emitting y_local.
// Outputs: Cbuf[bk][l][16], cumS[bk][l][c] (inclusive), ybuf[bk][l][c] (local y),
//          Hend[bk][ch][c][16] (chunk-local end state)
__global__ __launch_bounds__(192) void k_projscan(const float* __restrict__ x,
                                                  const float* __restrict__ xT,
                                                  const float* __restrict__ xpw,
                                                  const float* __restrict__ dtw,
                                                  const float* __restrict__ dt_bias,
                                                  const float* __restrict__ A_logs,
                                                  const float* __restrict__ Ds,
                                                  const float* __restrict__ ut0,
                                                  float* __restrict__ Cbuf,
                                                  float* __restrict__ cumS,
                                                  float* __restrict__ ybuf,
                                                  float* __restrict__ Hend) {
    int bid = blockIdx.x;                      // 8 * 144
    int bk = bid / NLT;
    int chk = bid % NLT;
    int lt0 = chk * LTILE;
    int b = bk >> 2, k = bk & 3;
    int tid = threadIdx.x;
    int lt = tid / ND;                         // 0..3 (l-group of 4), tid<176
    int dt = tid % ND;                         // 0..43
    __shared__ float WL[96 * 45];              // [cc][d] pad 45  17.3 KB
    __shared__ float XS[96 * LTILE];           // [cc][l]          6.1 KB
    __shared__ float DT[LTILE * NR];           // dts
    __shared__ float BL[LTILE * NN];           // B
    __shared__ float CL[LTILE * NN];           // C
    const float* bx = ((k & 1) ? xT : x) + (size_t)b * NCH * NL;
    bool rev = (k >= 2);
    float acc[4] = {0.0f, 0.0f, 0.0f, 0.0f};
    for (int ph = 0; ph < 2; ++ph) {
        int c0 = ph * 96;
        __syncthreads();
        for (int i = tid; i < 96 * ND; i += 192) {
            int d = i / 96, cc = i % 96;       // coalesced along cc
            WL[cc * 45 + d] = xpw[((size_t)k * ND + d) * NCH + c0 + cc];
        }
        for (int i = tid; i < 96 * LTILE; i += 192) {
            int cc = i >> 4, j = i & 15;
            int gl = lt0 + j;
            if (rev) gl = NL - 1 - gl;
            XS[i] = bx[(size_t)(c0 + cc) * NL + gl];
        }
        __syncthreads();
        if (tid < 4 * ND) {
#pragma unroll 8
            for (int cc = 0; cc < 96; ++cc) {
                float4 xv = *(const float4*)&XS[cc * LTILE + lt * 4];
                float wv = WL[cc * 45 + dt];
                acc[0] = fmaf(xv.x, wv, acc[0]);
                acc[1] = fmaf(xv.y, wv, acc[1]);
                acc[2] = fmaf(xv.z, wv, acc[2]);
                acc[3] = fmaf(xv.w, wv, acc[3]);
            }
        }
    }
    if (tid < 4 * ND) {
#pragma unroll
        for (int li = 0; li < 4; ++li) {
            int l = lt * 4 + li;               // within tile
            if (dt < NR) {
                DT[l * NR + dt] = acc[li];
            } else if (dt < NR + NN) {
                BL[l * NN + (dt - NR)] = acc[li];
            } else {
                CL[l * NN + (dt - NR - NN)] = acc[li];
                Cbuf[((size_t)bk * NL + lt0 + l) * NN + (dt - NR - NN)] = acc[li];
            }
        }
    }
    __syncthreads();
    // ------- tail: thread c does delta+softplus (ILP phase) then local scan
    int c = tid;
    float A2[NN];
    {
        const float4* ap = (const float4*)(A_logs + ((size_t)(k * NCH + c)) * NN);
        float4 a0 = ap[0], a1 = ap[1], a2 = ap[2], a3 = ap[3];
        float t[16] = {a0.x, a0.y, a0.z, a0.w, a1.x, a1.y, a1.z, a1.w,
                       a2.x, a2.y, a2.z, a2.w, a3.x, a3.y, a3.z, a3.w};
#pragma unroll
        for (int n = 0; n < NN; ++n) A2[n] = -expf(t[n]) * 1.44269504f;
    }
    const float4* wp = (const float4*)(dtw + ((size_t)k * NCH + c) * NR);
    float4 w0 = wp[0], w1 = wp[1], w2 = wp[2];
    float bias = dt_bias[k * NCH + c];
    float dval = Ds[k * NCH + c];
    const float* up = ut0 + (size_t)b * NL * NCH + c;
    float* csp = cumS + (size_t)bk * NL * NCH + c;
    float sp[CLEN], uvv[CLEN];
    float S = 0.0f;
#pragma unroll
    for (int i = 0; i < CLEN; ++i) {
        int l = lt0 + i;
        float4 a0 = *(const float4*)&DT[i * NR + 0];
        float4 a1 = *(const float4*)&DT[i * NR + 4];
        float4 a2 = *(const float4*)&DT[i * NR + 8];
        float p0 = fmaf(w0.x, a0.x, fmaf(w0.y, a0.y, bias));
        float p1 = fmaf(w0.z, a0.z, w0.w * a0.w);
        float p2 = fmaf(w1.x, a1.x, fmaf(w1.y, a1.y, w1.z * a1.z));
        float p3 = fmaf(w1.w, a1.w, fmaf(w2.x, a2.x, w2.y * a2.y));
        float p4 = fmaf(w2.z, a2.z, w2.w * a2.w);
        float acc2 = (p0 + p1) + (p2 + p3) + p4;
        float s = fmaxf(acc2, 0.0f) + log1pf(expf(-fabsf(acc2)));
        sp[i] = s;
        S += s;
        csp[(size_t)l * NCH] = S;
        uvv[i] = up[(size_t)u_row(k, l) * NCH];
    }
    float h[NN];
#pragma unroll
    for (int n = 0; n < NN; ++n) h[n] = 0.0f;
    float* yp = ybuf + (size_t)bk * NL * NCH + c;
#pragma unroll 4
    for (int i = 0; i < CLEN; ++i) {
        float du = sp[i] * uvv[i];
        const float4* br = (const float4*)&BL[i * NN];
        float4 b0 = br[0], b1 = br[1], b2 = br[2], b3 = br[3];
        float Bv[16] = {b0.x, b0.y, b0.z, b0.w, b1.x, b1.y, b1.z, b1.w,
                        b2.x, b2.y, b2.z, b2.w, b3.x, b3.y, b3.z, b3.w};
        const float4* cr = (const float4*)&CL[i * NN];
        float4 c0 = cr[0], c1 = cr[1], c2 = cr[2], c3 = cr[3];
        float Cv[16] = {c0.x, c0.y, c0.z, c0.w, c1.x, c1.y, c1.z, c1.w,
                        c2.x, c2.y, c2.z, c2.w, c3.x, c3.y, c3.z, c3.w};
        float y = 0.0f;
#pragma unroll
        for (int n = 0; n < NN; ++n) {
            float dA = exp2f(sp[i] * A2[n]);
            h[n] = fmaf(dA, h[n], du * Bv[n]);
            y = fmaf(h[n], Cv[n], y);
        }
        y = fmaf(dval, uvv[i], y);
        yp[(size_t)(lt0 + i) * NCH] = y;
    }
    size_t ob = (((size_t)bk * NCHUNK + chk) * NCH + c) * NN;
#pragma unroll
    for (int q = 0; q < 4; ++q)
        *(float4*)&Hend[ob + q * 4] =
            make_float4(h[q*4], h[q*4+1], h[q*4+2], h[q*4+3]);
}

// ------------- scan pass 2: chunk prefix in place (P from chunk-end cumS)
// After this kernel Hend[j] holds the INCOMING state for chunk j.
__global__ __launch_bounds__(256) void k_s2(const float* __restrict__ cumS,
                                            const float* __restrict__ A_logs,
                                            float* __restrict__ Hend) {
    int g = blockIdx.x * 256 + threadIdx.x;    // 0..24575
    int bk = g / (NCH * NN);
    int cn = g % (NCH * NN);
    int c = cn / NN, n = cn % NN;
    int k = bk & 3;
    float A2 = -expf(A_logs[((size_t)(k * NCH + c)) * NN + n]) * 1.44269504f;
    float h = 0.0f;
    const float* csp = cumS + (size_t)bk * NL * NCH + c;
    for (int j = 0; j < NCHUNK; ++j) {
        float S = csp[(size_t)(j * CLEN + CLEN - 1) * NCH];
        size_t idx = (((size_t)bk * NCHUNK + j) * NCH + c) * NN + n;
        float E = Hend[idx];
        float P = exp2f(S * A2);
        Hend[idx] = h;
        h = fmaf(P, h, E);
    }
}

// -------- fix: y += C · (exp2(cumS·A2) ∘ h_in)  — fully parallel, no syncs
__global__ __launch_bounds__(192) void k_fix(const float* __restrict__ Cbuf,
                                             const float* __restrict__ cumS,
                                             const float* __restrict__ Hin,
                                             const float* __restrict__ A_logs,
                                             float* __restrict__ ybuf) {
    int bid = blockIdx.x;                      // 8 * 144
    int bk = bid / NLT;
    int chk = bid % NLT;
    int lt0 = chk * LTILE;
    int k = bk & 3;
    int c = threadIdx.x;
    float A2[NN];
    {
        const float4* ap = (const float4*)(A_logs + ((size_t)(k * NCH + c)) * NN);
        float4 a0 = ap[0], a1 = ap[1], a2 = ap[2], a3 = ap[3];
        float t[16] = {a0.x, a0.y, a0.z, a0.w, a1.x, a1.y, a1.z, a1.w,
                       a2.x, a2.y, a2.z, a2.w, a3.x, a3.y, a3.z, a3.w};
#pragma unroll
        for (int n = 0; n < NN; ++n) A2[n] = -expf(t[n]) * 1.44269504f;
    }
    float hin[NN];
    {
        size_t ob = (((size_t)bk * NCHUNK + chk) * NCH + c) * NN;
        const float4* hp = (const float4*)(Hin + ob);
        float4 h0 = hp[0], h1 = hp[1], h2 = hp[2], h3 = hp[3];
        float t[16] = {h0.x, h0.y, h0.z, h0.w, h1.x, h1.y, h1.z, h1.w,
                       h2.x, h2.y, h2.z, h2.w, h3.x, h3.y, h3.z, h3.w};
#pragma unroll
        for (int n = 0; n < NN; ++n) hin[n] = t[n];
    }
    const float* csp = cumS + (size_t)bk * NL * NCH + c;
    float* yp = ybuf + (size_t)bk * NL * NCH + c;
#pragma unroll 4
    for (int i = 0; i < CLEN; ++i) {
        int l = lt0 + i;
        float cs = csp[(size_t)l * NCH];
        const float4* cr = (const float4*)(Cbuf + ((size_t)bk * NL + l) * NN);
        float4 c0 = cr[0], c1 = cr[1], c2 = cr[2], c3 = cr[3];
        float Cv[16] = {c0.x, c0.y, c0.z, c0.w, c1.x, c1.y, c1.z, c1.w,
                        c2.x, c2.y, c2.z, c2.w, c3.x, c3.y, c3.z, c3.w};
        float corr = 0.0f;
#pragma unroll
        for (int n = 0; n < NN; ++n) {
            float e = exp2f(cs * A2[n]);
            corr = fmaf(Cv[n] * hin[n], e, corr);
        }
        yp[(size_t)l * NCH] += corr;
    }
}

// ------------------------------------------- cross-merge from [bk][l][c]
__global__ __launch_bounds__(256) void k_merge(const float* __restrict__ ybuf,
                                               float* __restrict__ out) {
    int b = blockIdx.x / NH;
    int hh = blockIdx.x % NH;
    __shared__ float tile[NW * 193];
    const float* Y0 = ybuf + (size_t)(b * NK + 0) * NL * NCH;
    const float* Y1 = ybuf + (size_t)(b * NK + 1) * NL * NCH;
    const float* Y2 = ybuf + (size_t)(b * NK + 2) * NL * NCH;
    const float* Y3 = ybuf + (size_t)(b * NK + 3) * NL * NCH;
    for (int i = threadIdx.x; i < NW * NCH; i += 256) {
        int w = i / NCH, c = i % NCH;
        int hw = hh * NW + w;
        int wh = w * NH + hh;
        float v = Y0[(size_t)hw * NCH + c]
                + Y2[(size_t)(NL - 1 - hw) * NCH + c]
                + Y1[(size_t)wh * NCH + c]
                + Y3[(size_t)(NL - 1 - wh) * NCH + c];
        tile[w * 193 + c] = v;
    }
    __syncthreads();
    for (int i = threadIdx.x; i < NW * NCH; i += 256) {
        int c = i / NW, w = i % NW;
        out[((size_t)(b * NCH + c)) * NL + hh * NW + w] = tile[w * 193 + c];
    }
}

extern "C" void kernel_launch(void* const* d_in, const int* in_sizes, int n_in,
                              void* d_out, int out_size, void* d_ws, size_t ws_size,
                              hipStream_t stream) {
    const float* x      = (const float*)d_in[0];
    const float* xpw    = (const float*)d_in[1];
    const float* dtw    = (const float*)d_in[2];
    const float* A_logs = (const float*)d_in[3];
    const float* Ds     = (const float*)d_in[4];
    const float* dtb    = (const float*)d_in[5];
    float* out = (float*)d_out;

    float* ws = (float*)d_ws;
    float* xT    = ws;
    float* ut0   = xT + SZ_XT;
    float* Cbuf  = ut0 + SZ_UT0;
    float* cumS  = Cbuf + SZ_CB;
    float* ybuf  = cumS + SZ_CUMS;
    float* Hend  = ybuf + SZ_YBUF;   // after k_s2 holds Hin (in-place)

    k_prep<<<NB * NCH + NB * 36, 256, 0, stream>>>(x, xT, ut0);
    k_projscan<<<NB * NK * NLT, 192, 0, stream>>>(x, xT, xpw, dtw, dtb, A_logs,
                                                  Ds, ut0, Cbuf, cumS, ybuf, Hend);
    k_s2<<<(NB * NK * NCH * NN) / 256, 256, 0, stream>>>(cumS, A_logs, Hend);
    k_fix<<<NB * NK * NLT, 192, 0, stream>>>(Cbuf, cumS, Hend, A_logs, ybuf);
    k_merge<<<NB * NH, 256, 0, stream>>>(ybuf, out);
}